// Round 1
// baseline (493.882 us; speedup 1.0000x reference)
//
#include <hip/hip_runtime.h>

#define T_LEN   262144
#define KS      64
#define FD      16
#define EPSV    1e-10f
#define LOG2PI  1.8378770664093453f
#define L_CHUNK 128
#define BURN    64
#define C_CHUNKS (T_LEN / L_CHUNK)   // 2048

__device__ __forceinline__ float readlane_f(float v, int l) {
    return __uint_as_float((unsigned)__builtin_amdgcn_readlane((int)__float_as_uint(v), l));
}

__device__ __forceinline__ float wave_sum(float v) {
#pragma unroll
    for (int off = 32; off > 0; off >>= 1) v += __shfl_xor(v, off, 64);
    return v;
}

__device__ __forceinline__ float rcp_f(float v) { return __builtin_amdgcn_rcpf(v); }

__device__ __forceinline__ float emis(const float4 x[4], const float* Ac, const float* Bc, float cc) {
    float e = cc;
#pragma unroll
    for (int q = 0; q < 4; ++q) {
        e = fmaf(x[q].x, fmaf(Ac[q * 4 + 0], x[q].x, Bc[q * 4 + 0]), e);
        e = fmaf(x[q].y, fmaf(Ac[q * 4 + 1], x[q].y, Bc[q * 4 + 1]), e);
        e = fmaf(x[q].z, fmaf(Ac[q * 4 + 2], x[q].z, Bc[q * 4 + 2]), e);
        e = fmaf(x[q].w, fmaf(Ac[q * 4 + 3], x[q].w, Bc[q * 4 + 3]), e);
    }
    return e;
}

__device__ __forceinline__ void load_obs(const float* __restrict__ obs, int t, float4 x[4]) {
    const float4* o4 = (const float4*)(obs + (size_t)t * FD);
    x[0] = o4[0]; x[1] = o4[1]; x[2] = o4[2]; x[3] = o4[3];
}

extern "C" __global__ void __launch_bounds__(64)
hdphmm_fb(const float* __restrict__ obs, const float* __restrict__ beta_logits,
          const float* __restrict__ pi_logits, const float* __restrict__ means,
          const float* __restrict__ log_vars, float* __restrict__ out)
{
    __shared__ float lds_pi[KS * KS];
    __shared__ float lds_m[KS];
    __shared__ float lds_is[KS];

    const int lane   = threadIdx.x;          // block = 1 wave of 64
    const bool is_fwd = (blockIdx.x < C_CHUNKS);
    const int chunk  = is_fwd ? blockIdx.x : (blockIdx.x - C_CHUNKS);

    // ---- stage pi logits into LDS (16 KB) ----
    {
        const float4* src = (const float4*)pi_logits;
        float4* dst = (float4*)lds_pi;
#pragma unroll
        for (int i = 0; i < (KS * KS / 4) / 64; ++i) dst[lane + i * 64] = src[lane + i * 64];
    }
    __syncthreads();

    // ---- softmax row stats (row = lane) ----
    float rm = -1e30f;
    for (int j = 0; j < KS; ++j) rm = fmaxf(rm, lds_pi[lane * KS + j]);
    float rs = 0.f;
    for (int j = 0; j < KS; ++j) rs += __expf(lds_pi[lane * KS + j] - rm);
    lds_m[lane]  = rm;
    lds_is[lane] = rcp_f(rs);
    __syncthreads();

    // ---- transition fragment in registers ----
    // fwd: lane j holds column j of P (P[k][j]); bwd: lane j holds row j of P.
    float p[KS];
    if (is_fwd) {
#pragma unroll
        for (int k = 0; k < KS; ++k)
            p[k] = __expf(lds_pi[k * KS + lane] - lds_m[k]) * lds_is[k];
    } else {
        const float iis = lds_is[lane];
#pragma unroll
        for (int k = 0; k < KS; ++k)
            p[k] = __expf(lds_pi[lane * KS + k] - rm) * iis;
    }

    // ---- emission coefficients for state = lane ----
    // em(x) = cc + sum_f x_f * (Ac_f * x_f + Bc_f)
    float Ac[FD], Bc[FD];
    float cc = FD * LOG2PI;
#pragma unroll
    for (int f = 0; f < FD; ++f) {
        float lv = log_vars[lane * FD + f];
        float iv = __expf(-lv);
        float mu = means[lane * FD + f];
        Ac[f] = -0.5f * iv;
        Bc[f] = mu * iv;
        cc += lv + mu * mu * iv;
    }
    cc *= -0.5f;

    float* alpha = out;
    float* beta  = out + (size_t)T_LEN * KS;

    if (is_fwd) {
        const int lo = chunk * L_CHUNK, hi = lo + L_CHUNK;
        float a;
        int t0;
        float4 x[4];
        if (chunk == 0) {
            // exact stick-breaking init at t = 0
            float bl = beta_logits[lane];
            float sg = rcp_f(1.f + __expf(-bl));
            float om = 1.f - sg;
            float prod = om;
#pragma unroll
            for (int d = 1; d < 64; d <<= 1) {
                float u = __shfl_up(prod, d, 64);
                if (lane >= d) prod *= u;
            }
            float ex = __shfl_up(prod, 1, 64);
            float w = sg * (lane == 0 ? 1.f : ex);
            load_obs(obs, 0, x);
            float e = emis(x, Ac, Bc, cc);
            a = w * __expf(e);
            float s = wave_sum(a);
            a *= rcp_f(s + EPSV);
            alpha[lane] = a;
            t0 = 1;
        } else {
            a = 1.f / 64.f;          // uniform at t = lo - BURN; burn-in washes it out
            t0 = lo - BURN + 1;
        }
        load_obs(obs, t0, x);
        for (int t = t0; t < hi; ++t) {
            float4 xn[4];
            int tp = (t + 1 < T_LEN) ? (t + 1) : (T_LEN - 1);
            load_obs(obs, tp, xn);               // prefetch next row
            float e = emis(x, Ac, Bc, cc);
            float w = __expf(e);
            float acc0 = 0.f, acc1 = 0.f, acc2 = 0.f, acc3 = 0.f;
#pragma unroll
            for (int k = 0; k < KS; k += 4) {
                acc0 = fmaf(readlane_f(a, k + 0), p[k + 0], acc0);
                acc1 = fmaf(readlane_f(a, k + 1), p[k + 1], acc1);
                acc2 = fmaf(readlane_f(a, k + 2), p[k + 2], acc2);
                acc3 = fmaf(readlane_f(a, k + 3), p[k + 3], acc3);
            }
            float an = ((acc0 + acc1) + (acc2 + acc3)) * w;
            float s = wave_sum(an);
            an *= rcp_f(s + EPSV);
            a = an;
            if (t >= lo) alpha[(size_t)t * KS + lane] = a;
            x[0] = xn[0]; x[1] = xn[1]; x[2] = xn[2]; x[3] = xn[3];
        }
        if (hi == T_LEN) {
            float s2 = wave_sum(a);
            if (lane == 0) out[(size_t)2 * T_LEN * KS] = __logf(s2 + EPSV);
        }
    } else {
        const int lo = chunk * L_CHUNK, hi = lo + L_CHUNK;
        float b = 1.f;
        int tstart;
        if (hi == T_LEN) {
            beta[(size_t)(T_LEN - 1) * KS + lane] = 1.f;   // exact bT
            tstart = T_LEN - 2;
        } else {
            tstart = hi - 1 + BURN - 1;  // ones at t = hi-1+BURN, burn down into [lo,hi)
        }
        float4 x[4];
        load_obs(obs, tstart + 1, x);
        for (int t = tstart; t >= lo; --t) {
            float4 xn[4];
            load_obs(obs, (t > 0) ? t : 0, xn);  // prefetch row t (next iter's t+1)
            float e = emis(x, Ac, Bc, cc);       // em[t+1][lane]
            float v = b * __expf(e);
            float acc0 = 0.f, acc1 = 0.f, acc2 = 0.f, acc3 = 0.f;
#pragma unroll
            for (int k = 0; k < KS; k += 4) {
                acc0 = fmaf(readlane_f(v, k + 0), p[k + 0], acc0);
                acc1 = fmaf(readlane_f(v, k + 1), p[k + 1], acc1);
                acc2 = fmaf(readlane_f(v, k + 2), p[k + 2], acc2);
                acc3 = fmaf(readlane_f(v, k + 3), p[k + 3], acc3);
            }
            float bn = (acc0 + acc1) + (acc2 + acc3);
            float s = wave_sum(bn);
            bn *= rcp_f(s + EPSV);
            b = bn;
            if (t < hi) beta[(size_t)t * KS + lane] = b;
            x[0] = xn[0]; x[1] = xn[1]; x[2] = xn[2]; x[3] = xn[3];
        }
    }
}

extern "C" void kernel_launch(void* const* d_in, const int* in_sizes, int n_in,
                              void* d_out, int out_size, void* d_ws, size_t ws_size,
                              hipStream_t stream) {
    const float* obs         = (const float*)d_in[0];
    const float* beta_logits = (const float*)d_in[1];
    const float* pi_logits   = (const float*)d_in[2];
    const float* means       = (const float*)d_in[3];
    const float* log_vars    = (const float*)d_in[4];
    float* out = (float*)d_out;
    (void)in_sizes; (void)n_in; (void)out_size; (void)d_ws; (void)ws_size;

    hipLaunchKernelGGL(hdphmm_fb, dim3(2 * C_CHUNKS), dim3(64), 0, stream,
                       obs, beta_logits, pi_logits, means, log_vars, out);
}

// Round 3
// 393.667 us; speedup vs baseline: 1.2546x; 1.2546x over previous
//
#include <hip/hip_runtime.h>

#define T_LEN   262144
#define KS      64
#define FD      16
#define EPSV    1e-10f
#define LOG2PI  1.8378770664093453f
#define L_CHUNK 128
#define BURN    24
#define C_CHUNKS (T_LEN / L_CHUNK)   // 2048

__device__ __forceinline__ float readlane_f(float v, int l) {
    return __uint_as_float((unsigned)__builtin_amdgcn_readlane((int)__float_as_uint(v), l));
}

__device__ __forceinline__ float wave_sum(float v) {
#pragma unroll
    for (int off = 32; off > 0; off >>= 1) v += __shfl_xor(v, off, 64);
    return v;
}

__device__ __forceinline__ float rcp_f(float v) { return __builtin_amdgcn_rcpf(v); }

__device__ __forceinline__ float emis(const float4 x[4], const float* Ac, const float* Bc, float cc) {
    float e = cc;
#pragma unroll
    for (int q = 0; q < 4; ++q) {
        e = fmaf(x[q].x, fmaf(Ac[q * 4 + 0], x[q].x, Bc[q * 4 + 0]), e);
        e = fmaf(x[q].y, fmaf(Ac[q * 4 + 1], x[q].y, Bc[q * 4 + 1]), e);
        e = fmaf(x[q].z, fmaf(Ac[q * 4 + 2], x[q].z, Bc[q * 4 + 2]), e);
        e = fmaf(x[q].w, fmaf(Ac[q * 4 + 3], x[q].w, Bc[q * 4 + 3]), e);
    }
    return e;
}

__device__ __forceinline__ void load_obs(const float* __restrict__ obs, int t, float4 x[4]) {
    const float4* o4 = (const float4*)(obs + (size_t)t * FD);
    x[0] = o4[0]; x[1] = o4[1]; x[2] = o4[2]; x[3] = o4[3];
}

__device__ __forceinline__ float matvec64(float a, const float* p) {
    float acc0 = 0.f, acc1 = 0.f, acc2 = 0.f, acc3 = 0.f;
#pragma unroll
    for (int k = 0; k < KS; k += 4) {
        acc0 = fmaf(readlane_f(a, k + 0), p[k + 0], acc0);
        acc1 = fmaf(readlane_f(a, k + 1), p[k + 1], acc1);
        acc2 = fmaf(readlane_f(a, k + 2), p[k + 2], acc2);
        acc3 = fmaf(readlane_f(a, k + 3), p[k + 3], acc3);
    }
    return (acc0 + acc1) + (acc2 + acc3);
}

extern "C" __global__ void __launch_bounds__(64)
hdphmm_fb(const float* __restrict__ obs, const float* __restrict__ beta_logits,
          const float* __restrict__ pi_logits, const float* __restrict__ means,
          const float* __restrict__ log_vars, float* __restrict__ out)
{
    __shared__ float lds_m[KS];    // per-row softmax max
    __shared__ float lds_is[KS];   // per-row 1/sum

    const int lane    = threadIdx.x;          // block = 1 wave of 64
    const bool is_fwd = (blockIdx.x < C_CHUNKS);
    const int chunk   = is_fwd ? blockIdx.x : (blockIdx.x - C_CHUNKS);

    // ---- transition fragment: lane's own row of pi (16 KB, L1-resident) ----
    float p[KS];
#pragma unroll
    for (int k = 0; k < KS; ++k) p[k] = pi_logits[lane * KS + k];
    float rm = -1e30f;
#pragma unroll
    for (int k = 0; k < KS; ++k) rm = fmaxf(rm, p[k]);
    float rs = 0.f;
#pragma unroll
    for (int k = 0; k < KS; ++k) rs += __expf(p[k] - rm);
    lds_m[lane]  = rm;
    lds_is[lane] = rcp_f(rs);
    __syncthreads();

    if (is_fwd) {
        // fwd: lane j holds column j of P (coalesced column reload)
#pragma unroll
        for (int k = 0; k < KS; ++k)
            p[k] = __expf(pi_logits[k * KS + lane] - lds_m[k]) * lds_is[k];
    } else {
        // bwd: lane j holds row j of P (already in regs)
        const float iis = lds_is[lane];
#pragma unroll
        for (int k = 0; k < KS; ++k)
            p[k] = __expf(p[k] - rm) * iis;
    }

    // ---- emission coefficients for state = lane ----
    float Ac[FD], Bc[FD];
    float cc = FD * LOG2PI;
#pragma unroll
    for (int f = 0; f < FD; ++f) {
        float lv = log_vars[lane * FD + f];
        float iv = __expf(-lv);
        float mu = means[lane * FD + f];
        Ac[f] = -0.5f * iv;
        Bc[f] = mu * iv;
        cc += lv + mu * mu * iv;
    }
    cc *= -0.5f;

    float* alpha = out;
    float* betap = out + (size_t)T_LEN * KS;

    if (is_fwd) {
        const int lo = chunk * L_CHUNK, hi = lo + L_CHUNK;
        float a;            // unnormalized state (reference's pre-division a-tilde)
        float c_lag = 1.f;  // 1/(prev sum + EPS): carries the reference's eps semantics
        float s = 0.f;
        int t0;
        float4 x[4];
        if (chunk == 0) {
            // exact stick-breaking init at t = 0
            float bl = beta_logits[lane];
            float sg = rcp_f(1.f + __expf(-bl));
            float om = 1.f - sg;
            float prod = om;
#pragma unroll
            for (int d = 1; d < 64; d <<= 1) {
                float u = __shfl_up(prod, d, 64);
                if (lane >= d) prod *= u;
            }
            float ex = __shfl_up(prod, 1, 64);
            float w0 = sg * (lane == 0 ? 1.f : ex);
            load_obs(obs, 0, x);
            float e = emis(x, Ac, Bc, cc);
            a = w0 * __expf(e);
            s = wave_sum(a);
            alpha[lane] = a * rcp_f(s + EPSV);
            c_lag = rcp_f(s + EPSV);   // KEEP EPS: reference divides by (sum+eps)
            t0 = 1;
        } else {
            a = 1.f / 64.f;          // arbitrary init; eps-dynamics forget it in burn-in
            t0 = lo - BURN + 1;
        }
        load_obs(obs, t0, x);
        for (int t = t0; t < hi; ++t) {
            float4 xn[4];
            int tp = (t + 1 < T_LEN) ? (t + 1) : (T_LEN - 1);
            load_obs(obs, tp, xn);                 // prefetch next row
            float e = emis(x, Ac, Bc, cc);         // independent of a-chain
            float wc = __expf(e) * c_lag;
            float m = matvec64(a, p);              // the only a-dependent part
            float an = m * wc;
            s = wave_sum(an);                      // side chain — rejoins next iter
            if (t >= lo) alpha[(size_t)t * KS + lane] = an * rcp_f(s + EPSV);
            c_lag = rcp_f(s + EPSV);               // KEEP EPS (collapse semantics!)
            a = an;
            x[0] = xn[0]; x[1] = xn[1]; x[2] = xn[2]; x[3] = xn[3];
        }
        if (hi == T_LEN) {
            float s2 = wave_sum(a * rcp_f(s + EPSV));  // sum(alpha[-1])
            if (lane == 0) out[(size_t)2 * T_LEN * KS] = __logf(s2 + EPSV);
        }
    } else {
        const int lo = chunk * L_CHUNK, hi = lo + L_CHUNK;
        float b = 1.f;      // unnormalized state
        float c_lag = 1.f;  // first step from bT uses no division (reference semantics)
        int tstart;
        if (hi == T_LEN) {
            betap[(size_t)(T_LEN - 1) * KS + lane] = 1.f;   // exact bT
            tstart = T_LEN - 2;
        } else {
            tstart = hi - 1 + BURN - 1;  // ones above; burn down into [lo,hi)
        }
        float4 x[4];
        load_obs(obs, tstart + 1, x);
        for (int t = tstart; t >= lo; --t) {
            float4 xn[4];
            load_obs(obs, (t > 0) ? t : 0, xn);    // prefetch row t
            float e = emis(x, Ac, Bc, cc);         // em[t+1][lane]
            float wc = __expf(e) * c_lag;
            float v = b * wc;
            float bn = matvec64(v, p);
            float s = wave_sum(bn);                // side chain
            if (t < hi) betap[(size_t)t * KS + lane] = bn * rcp_f(s + EPSV);
            c_lag = rcp_f(s + EPSV);               // KEEP EPS
            b = bn;
            x[0] = xn[0]; x[1] = xn[1]; x[2] = xn[2]; x[3] = xn[3];
        }
    }
}

extern "C" void kernel_launch(void* const* d_in, const int* in_sizes, int n_in,
                              void* d_out, int out_size, void* d_ws, size_t ws_size,
                              hipStream_t stream) {
    const float* obs         = (const float*)d_in[0];
    const float* beta_logits = (const float*)d_in[1];
    const float* pi_logits   = (const float*)d_in[2];
    const float* means       = (const float*)d_in[3];
    const float* log_vars    = (const float*)d_in[4];
    float* out = (float*)d_out;
    (void)in_sizes; (void)n_in; (void)out_size; (void)d_ws; (void)ws_size;

    hipLaunchKernelGGL(hdphmm_fb, dim3(2 * C_CHUNKS), dim3(64), 0, stream,
                       obs, beta_logits, pi_logits, means, log_vars, out);
}

// Round 4
// 369.404 us; speedup vs baseline: 1.3370x; 1.0657x over previous
//
#include <hip/hip_runtime.h>

#define T_LEN   262144
#define KS      64
#define FD      16
#define EPSV    1e-10f
#define LOG2PI  1.8378770664093453f
#define L_CHUNK 128
#define BURN    24
#define C_CHUNKS (T_LEN / L_CHUNK)   // 2048
#define WPB     4                    // waves per block

__device__ __forceinline__ float readlane_f(float v, int l) {
    return __uint_as_float((unsigned)__builtin_amdgcn_readlane((int)__float_as_uint(v), l));
}

__device__ __forceinline__ float wave_sum(float v) {
#pragma unroll
    for (int off = 32; off > 0; off >>= 1) v += __shfl_xor(v, off, 64);
    return v;
}

__device__ __forceinline__ float rcp_f(float v) { return __builtin_amdgcn_rcpf(v); }

__device__ __forceinline__ float emis(const float4 x[4], const float* Ac, const float* Bc, float cc) {
    float e = cc;
#pragma unroll
    for (int q = 0; q < 4; ++q) {
        e = fmaf(x[q].x, fmaf(Ac[q * 4 + 0], x[q].x, Bc[q * 4 + 0]), e);
        e = fmaf(x[q].y, fmaf(Ac[q * 4 + 1], x[q].y, Bc[q * 4 + 1]), e);
        e = fmaf(x[q].z, fmaf(Ac[q * 4 + 2], x[q].z, Bc[q * 4 + 2]), e);
        e = fmaf(x[q].w, fmaf(Ac[q * 4 + 3], x[q].w, Bc[q * 4 + 3]), e);
    }
    return e;
}

__device__ __forceinline__ void load_obs(const float* __restrict__ obs, int t, float4 x[4]) {
    const float4* o4 = (const float4*)(obs + (size_t)t * FD);
    x[0] = o4[0]; x[1] = o4[1]; x[2] = o4[2]; x[3] = o4[3];
}

__device__ __forceinline__ float matvec64(float a, const float* p) {
    float acc0 = 0.f, acc1 = 0.f, acc2 = 0.f, acc3 = 0.f;
#pragma unroll
    for (int k = 0; k < KS; k += 4) {
        acc0 = fmaf(readlane_f(a, k + 0), p[k + 0], acc0);
        acc1 = fmaf(readlane_f(a, k + 1), p[k + 1], acc1);
        acc2 = fmaf(readlane_f(a, k + 2), p[k + 2], acc2);
        acc3 = fmaf(readlane_f(a, k + 3), p[k + 3], acc3);
    }
    return (acc0 + acc1) + (acc2 + acc3);
}

extern "C" __global__ void __launch_bounds__(WPB * 64)
hdphmm_fb(const float* __restrict__ obs, const float* __restrict__ beta_logits,
          const float* __restrict__ pi_logits, const float* __restrict__ means,
          const float* __restrict__ log_vars, float* __restrict__ out)
{
    const int lane = threadIdx.x & 63;
    const int g    = blockIdx.x * WPB + (threadIdx.x >> 6);   // global wave id
    const bool is_fwd = (g < C_CHUNKS);
    const int chunk   = is_fwd ? g : (g - C_CHUNKS);

    // ---- per-row softmax stats (row = lane), shared via readlane, no LDS ----
    float p[KS];
#pragma unroll
    for (int k = 0; k < KS; ++k) p[k] = pi_logits[lane * KS + k];
    float rm = -1e30f;
#pragma unroll
    for (int k = 0; k < KS; ++k) rm = fmaxf(rm, p[k]);
    float rs = 0.f;
#pragma unroll
    for (int k = 0; k < KS; ++k) rs += __expf(p[k] - rm);
    float ris = rcp_f(rs);

    if (is_fwd) {
        // fwd: lane j holds column j of P (coalesced column reload; setup-only)
#pragma unroll
        for (int k = 0; k < KS; ++k) {
            float mk = readlane_f(rm, k);
            float ik = readlane_f(ris, k);
            p[k] = __expf(pi_logits[k * KS + lane] - mk) * ik;
        }
    } else {
        // bwd: lane j holds row j of P (already in regs)
#pragma unroll
        for (int k = 0; k < KS; ++k)
            p[k] = __expf(p[k] - rm) * ris;
    }

    // ---- emission coefficients for state = lane ----
    float Ac[FD], Bc[FD];
    float cc = FD * LOG2PI;
#pragma unroll
    for (int f = 0; f < FD; ++f) {
        float lv = log_vars[lane * FD + f];
        float iv = __expf(-lv);
        float mu = means[lane * FD + f];
        Ac[f] = -0.5f * iv;
        Bc[f] = mu * iv;
        cc += lv + mu * mu * iv;
    }
    cc *= -0.5f;

    float* alpha = out;
    float* betap = out + (size_t)T_LEN * KS;

    if (is_fwd) {
        const int lo = chunk * L_CHUNK, hi = lo + L_CHUNK;
        float a;            // unnormalized state (reference's pre-division a-tilde)
        float c_lag = 1.f;  // 1/(prev sum + EPS): carries the reference's eps semantics
        float s = 0.f;
        int t0;
        float4 x[4];
        if (chunk == 0) {
            // exact stick-breaking init at t = 0
            float bl = beta_logits[lane];
            float sg = rcp_f(1.f + __expf(-bl));
            float om = 1.f - sg;
            float prod = om;
#pragma unroll
            for (int d = 1; d < 64; d <<= 1) {
                float u = __shfl_up(prod, d, 64);
                if (lane >= d) prod *= u;
            }
            float ex = __shfl_up(prod, 1, 64);
            float w0 = sg * (lane == 0 ? 1.f : ex);
            load_obs(obs, 0, x);
            float e = emis(x, Ac, Bc, cc);
            a = w0 * __expf(e);
            s = wave_sum(a);
            alpha[lane] = a * rcp_f(s + EPSV);
            c_lag = rcp_f(s + EPSV);   // KEEP EPS: reference divides by (sum+eps)
            t0 = 1;
        } else {
            a = 1.f / 64.f;            // arbitrary init; eps-dynamics forget it in burn-in
            t0 = lo - BURN + 1;
        }
        load_obs(obs, t0, x);
        for (int t = t0; t < hi; ++t) {
            float4 xn[4];
            int tp = (t + 1 < T_LEN) ? (t + 1) : (T_LEN - 1);
            load_obs(obs, tp, xn);                 // prefetch next row
            float e = emis(x, Ac, Bc, cc);         // independent of a-chain
            float wc = __expf(e) * c_lag;
            float m = matvec64(a, p);              // the only a-dependent part
            float an = m * wc;
            s = wave_sum(an);                      // side chain — rejoins next iter
            if (t >= lo) alpha[(size_t)t * KS + lane] = an * rcp_f(s + EPSV);
            c_lag = rcp_f(s + EPSV);               // KEEP EPS (collapse semantics!)
            a = an;
            x[0] = xn[0]; x[1] = xn[1]; x[2] = xn[2]; x[3] = xn[3];
        }
        if (hi == T_LEN) {
            float s2 = wave_sum(a * rcp_f(s + EPSV));  // sum(alpha[-1])
            if (lane == 0) out[(size_t)2 * T_LEN * KS] = __logf(s2 + EPSV);
        }
    } else {
        const int lo = chunk * L_CHUNK, hi = lo + L_CHUNK;
        float b = 1.f;      // unnormalized state
        float c_lag = 1.f;  // first step from bT uses no division (reference semantics)
        int tstart;
        if (hi == T_LEN) {
            betap[(size_t)(T_LEN - 1) * KS + lane] = 1.f;   // exact bT
            tstart = T_LEN - 2;
        } else {
            tstart = hi - 1 + BURN - 1;  // ones above; burn down into [lo,hi)
        }
        float4 x[4];
        load_obs(obs, tstart + 1, x);
        for (int t = tstart; t >= lo; --t) {
            float4 xn[4];
            load_obs(obs, (t > 0) ? t : 0, xn);    // prefetch row t
            float e = emis(x, Ac, Bc, cc);         // em[t+1][lane]
            float wc = __expf(e) * c_lag;
            float v = b * wc;
            float bn = matvec64(v, p);
            float s = wave_sum(bn);                // side chain
            if (t < hi) betap[(size_t)t * KS + lane] = bn * rcp_f(s + EPSV);
            c_lag = rcp_f(s + EPSV);               // KEEP EPS
            b = bn;
            x[0] = xn[0]; x[1] = xn[1]; x[2] = xn[2]; x[3] = xn[3];
        }
    }
}

extern "C" void kernel_launch(void* const* d_in, const int* in_sizes, int n_in,
                              void* d_out, int out_size, void* d_ws, size_t ws_size,
                              hipStream_t stream) {
    const float* obs         = (const float*)d_in[0];
    const float* beta_logits = (const float*)d_in[1];
    const float* pi_logits   = (const float*)d_in[2];
    const float* means       = (const float*)d_in[3];
    const float* log_vars    = (const float*)d_in[4];
    float* out = (float*)d_out;
    (void)in_sizes; (void)n_in; (void)out_size; (void)d_ws; (void)ws_size;

    hipLaunchKernelGGL(hdphmm_fb, dim3(2 * C_CHUNKS / WPB), dim3(WPB * 64), 0, stream,
                       obs, beta_logits, pi_logits, means, log_vars, out);
}

// Round 5
// 349.404 us; speedup vs baseline: 1.4135x; 1.0572x over previous
//
#include <hip/hip_runtime.h>

#define T_LEN   262144
#define KS      64
#define FD      16
#define EPSV    1e-10f
#define LOG2PI  1.8378770664093453f
#define L_CHUNK 128
#define BURN    16
#define C_CHUNKS (T_LEN / L_CHUNK)   // 2048
#define WPB     4                    // waves per block

__device__ __forceinline__ float readlane_f(float v, int l) {
    return __uint_as_float((unsigned)__builtin_amdgcn_readlane((int)__float_as_uint(v), l));
}

__device__ __forceinline__ float wave_sum(float v) {
#pragma unroll
    for (int off = 32; off > 0; off >>= 1) v += __shfl_xor(v, off, 64);
    return v;
}

__device__ __forceinline__ float rcp_f(float v) { return __builtin_amdgcn_rcpf(v); }

__device__ __forceinline__ float emis(const float4 x[4], const float* Ac, const float* Bc, float cc) {
    float e = cc;
#pragma unroll
    for (int q = 0; q < 4; ++q) {
        e = fmaf(x[q].x, fmaf(Ac[q * 4 + 0], x[q].x, Bc[q * 4 + 0]), e);
        e = fmaf(x[q].y, fmaf(Ac[q * 4 + 1], x[q].y, Bc[q * 4 + 1]), e);
        e = fmaf(x[q].z, fmaf(Ac[q * 4 + 2], x[q].z, Bc[q * 4 + 2]), e);
        e = fmaf(x[q].w, fmaf(Ac[q * 4 + 3], x[q].w, Bc[q * 4 + 3]), e);
    }
    return e;
}

__device__ __forceinline__ void load_obs(const float* __restrict__ obs, int t, float4 x[4]) {
    const float4* o4 = (const float4*)(obs + (size_t)t * FD);
    x[0] = o4[0]; x[1] = o4[1]; x[2] = o4[2]; x[3] = o4[3];
}

__device__ __forceinline__ float matvec64(float a, const float* p) {
    float acc0 = 0.f, acc1 = 0.f, acc2 = 0.f, acc3 = 0.f;
#pragma unroll
    for (int k = 0; k < KS; k += 4) {
        acc0 = fmaf(readlane_f(a, k + 0), p[k + 0], acc0);
        acc1 = fmaf(readlane_f(a, k + 1), p[k + 1], acc1);
        acc2 = fmaf(readlane_f(a, k + 2), p[k + 2], acc2);
        acc3 = fmaf(readlane_f(a, k + 3), p[k + 3], acc3);
    }
    return (acc0 + acc1) + (acc2 + acc3);
}

extern "C" __global__ void __launch_bounds__(WPB * 64)
hdphmm_fb(const float* __restrict__ obs, const float* __restrict__ beta_logits,
          const float* __restrict__ pi_logits, const float* __restrict__ means,
          const float* __restrict__ log_vars, float* __restrict__ out)
{
    const int lane = threadIdx.x & 63;
    const int g    = blockIdx.x * WPB + (threadIdx.x >> 6);   // global wave id
    const bool is_fwd = (g < C_CHUNKS);
    const int chunk   = is_fwd ? g : (g - C_CHUNKS);

    // ---- per-row softmax stats (row = lane), shared via readlane, no LDS ----
    float p[KS];
#pragma unroll
    for (int k = 0; k < KS; ++k) p[k] = pi_logits[lane * KS + k];
    float rm = -1e30f;
#pragma unroll
    for (int k = 0; k < KS; ++k) rm = fmaxf(rm, p[k]);
    float rs = 0.f;
#pragma unroll
    for (int k = 0; k < KS; ++k) rs += __expf(p[k] - rm);
    float ris = rcp_f(rs);

    if (is_fwd) {
        // fwd: lane j holds column j of P (coalesced column reload; setup-only)
#pragma unroll
        for (int k = 0; k < KS; ++k) {
            float mk = readlane_f(rm, k);
            float ik = readlane_f(ris, k);
            p[k] = __expf(pi_logits[k * KS + lane] - mk) * ik;
        }
    } else {
        // bwd: lane j holds row j of P (already in regs)
#pragma unroll
        for (int k = 0; k < KS; ++k)
            p[k] = __expf(p[k] - rm) * ris;
    }

    // ---- emission coefficients for state = lane ----
    float Ac[FD], Bc[FD];
    float cc = FD * LOG2PI;
#pragma unroll
    for (int f = 0; f < FD; ++f) {
        float lv = log_vars[lane * FD + f];
        float iv = __expf(-lv);
        float mu = means[lane * FD + f];
        Ac[f] = -0.5f * iv;
        Bc[f] = mu * iv;
        cc += lv + mu * mu * iv;
    }
    cc *= -0.5f;

    float* alpha = out;
    float* betap = out + (size_t)T_LEN * KS;

    // Deferred-normalization bookkeeping (exact eps semantics):
    //   propagated A_t = rho_t * atilde_t;  s_t = S_t * invrho_t;  u_t = s_t + EPS
    //   transition applies invu from two steps back; invrho_t = invrho_{t-1}*u_{t-2}*invu_{t-1}
    //   store: ref_row = A * invrho * invu   (one step late)

    if (is_fwd) {
        const int lo = chunk * L_CHUNK, hi = lo + L_CHUNK;
        float a, S;
        float invrho = 1.f, u_prev = 1.f, invu_prev = 1.f;
        float4 x[4];
        int tau0, burn_end;
        if (chunk == 0) {
            // exact stick-breaking init at t = 0 : A_0 = atilde_0
            float bl = beta_logits[lane];
            float sg = rcp_f(1.f + __expf(-bl));
            float om = 1.f - sg;
            float prod = om;
#pragma unroll
            for (int d = 1; d < 64; d <<= 1) {
                float u = __shfl_up(prod, d, 64);
                if (lane >= d) prod *= u;
            }
            float ex = __shfl_up(prod, 1, 64);
            float w0 = sg * (lane == 0 ? 1.f : ex);
            load_obs(obs, 0, x);
            float e = emis(x, Ac, Bc, cc);
            a = w0 * __expf(e);
            S = wave_sum(a);
            tau0 = 1; burn_end = 1;
            load_obs(obs, 1, x);
        } else {
            a = 1.f / 64.f;   // arbitrary; burn-in forgets it
            S = 1.f;          // wave_sum of the uniform init, known exactly
            tau0 = lo - BURN + 1; burn_end = lo + 1;
            load_obs(obs, tau0, x);
        }
        // ---- burn loop: produce A_tau for tau in [tau0, burn_end), no stores ----
        for (int tau = tau0; tau < burn_end; ++tau) {
            float4 xn[4];
            load_obs(obs, tau + 1, xn);            // tau+1 <= lo+1 < T
            float e = emis(x, Ac, Bc, cc);
            float w = __expf(e) * invu_prev;
            float an = matvec64(a, p) * w;         // A_tau
            float s_t = S * invrho;                // s_{tau-1}
            float u = s_t + EPSV;
            float invu = rcp_f(u);
            invrho = invrho * u_prev * invu;
            u_prev = u; invu_prev = invu;
            S = wave_sum(an);
            a = an;
            x[0] = xn[0]; x[1] = xn[1]; x[2] = xn[2]; x[3] = xn[3];
        }
        // ---- main loop: produce A_tau, store row tau-1 ----
        float* outp = alpha + (size_t)(burn_end - 1) * KS + lane;
        for (int tau = burn_end; tau < hi; ++tau) {
            float4 xn[4];
            int tp = (tau + 1 < T_LEN) ? (tau + 1) : (T_LEN - 1);
            load_obs(obs, tp, xn);
            float e = emis(x, Ac, Bc, cc);
            float w = __expf(e) * invu_prev;
            float an = matvec64(a, p) * w;         // A_tau
            float s_t = S * invrho;                // s_{tau-1}
            float u = s_t + EPSV;
            float invu = rcp_f(u);
            *outp = a * (invrho * invu);           // ref row tau-1
            outp += KS;
            invrho = invrho * u_prev * invu;
            u_prev = u; invu_prev = invu;
            S = wave_sum(an);
            a = an;
            x[0] = xn[0]; x[1] = xn[1]; x[2] = xn[2]; x[3] = xn[3];
        }
        // ---- epilogue: store row hi-1 ----
        float s_t = S * invrho;
        float u = s_t + EPSV;
        float invu = rcp_f(u);
        *outp = a * (invrho * invu);
        if (hi == T_LEN) {
            float sa = s_t * invu;                 // sum(alpha[T-1])
            if (lane == 0) out[(size_t)2 * T_LEN * KS] = __logf(sa + EPSV);
        }
    } else {
        const int lo = chunk * L_CHUNK, hi = lo + L_CHUNK;
        float b, S;
        float invrho = 1.f, u_prev = 1.f, invu_prev = 1.f;
        float4 x[4];
        int main_start;
        if (hi == T_LEN) {
            betap[(size_t)(T_LEN - 1) * KS + lane] = 1.f;     // exact bT
            // peeled first step (tau = T-2): reference applies NO division to bT
            load_obs(obs, T_LEN - 1, x);
            float e = emis(x, Ac, Bc, cc);
            float bn = matvec64(__expf(e), p);     // b = 1
            S = wave_sum(bn);
            b = bn;
            load_obs(obs, T_LEN - 2, x);           // row tau+1 for tau = T-3
            main_start = T_LEN - 3;
        } else {
            b = 1.f;      // arbitrary ones; burn-in forgets it
            S = 64.f;     // wave_sum of ones, known exactly
            int tstart = hi + BURN - 2;
            load_obs(obs, tstart + 1, x);
            // ---- burn loop: produce B_tau for tau in [hi-1, tstart], no stores ----
            for (int tau = tstart; tau >= hi - 1; --tau) {
                float4 xn[4];
                load_obs(obs, tau, xn);
                float e = emis(x, Ac, Bc, cc);
                float w = __expf(e) * invu_prev;
                float bn = matvec64(b * w, p);     // B_tau
                float s_t = S * invrho;
                float u = s_t + EPSV;
                float invu = rcp_f(u);
                invrho = invrho * u_prev * invu;
                u_prev = u; invu_prev = invu;
                S = wave_sum(bn);
                b = bn;
                x[0] = xn[0]; x[1] = xn[1]; x[2] = xn[2]; x[3] = xn[3];
            }
            main_start = hi - 2;
        }
        // ---- main loop: produce B_tau, store row tau+1 ----
        float* outp = betap + (size_t)(main_start + 1) * KS + lane;
        for (int tau = main_start; tau >= lo; --tau) {
            float4 xn[4];
            load_obs(obs, tau, xn);                // row tau (next iter's tau+1)
            float e = emis(x, Ac, Bc, cc);         // em[tau+1]
            float w = __expf(e) * invu_prev;
            float bn = matvec64(b * w, p);         // B_tau
            float s_t = S * invrho;                // stilde_{tau+1}
            float u = s_t + EPSV;
            float invu = rcp_f(u);
            *outp = b * (invrho * invu);           // ref row tau+1
            outp -= KS;
            invrho = invrho * u_prev * invu;
            u_prev = u; invu_prev = invu;
            S = wave_sum(bn);
            b = bn;
            x[0] = xn[0]; x[1] = xn[1]; x[2] = xn[2]; x[3] = xn[3];
        }
        // ---- epilogue: store row lo ----
        float s_t = S * invrho;
        float u = s_t + EPSV;
        float invu = rcp_f(u);
        *outp = b * (invrho * invu);
    }
}

extern "C" void kernel_launch(void* const* d_in, const int* in_sizes, int n_in,
                              void* d_out, int out_size, void* d_ws, size_t ws_size,
                              hipStream_t stream) {
    const float* obs         = (const float*)d_in[0];
    const float* beta_logits = (const float*)d_in[1];
    const float* pi_logits   = (const float*)d_in[2];
    const float* means       = (const float*)d_in[3];
    const float* log_vars    = (const float*)d_in[4];
    float* out = (float*)d_out;
    (void)in_sizes; (void)n_in; (void)out_size; (void)d_ws; (void)ws_size;

    hipLaunchKernelGGL(hdphmm_fb, dim3(2 * C_CHUNKS / WPB), dim3(WPB * 64), 0, stream,
                       obs, beta_logits, pi_logits, means, log_vars, out);
}

// Round 6
// 344.171 us; speedup vs baseline: 1.4350x; 1.0152x over previous
//
#include <hip/hip_runtime.h>

#define T_LEN   262144
#define KS      64
#define FD      16
#define EPSV    1e-10f
#define LOG2PI  1.8378770664093453f
#define L_CHUNK 128
#define BURN    18
#define C_CHUNKS (T_LEN / L_CHUNK)   // 2048
#define WPB     4                    // waves per block

__device__ __forceinline__ float readlane_f(float v, int l) {
    return __uint_as_float((unsigned)__builtin_amdgcn_readlane((int)__float_as_uint(v), l));
}

__device__ __forceinline__ float wave_sum(float v) {
#pragma unroll
    for (int off = 32; off > 0; off >>= 1) v += __shfl_xor(v, off, 64);
    return v;
}

__device__ __forceinline__ float rcp_f(float v) { return __builtin_amdgcn_rcpf(v); }

__device__ __forceinline__ float emis(const float4 x[4], const float* Ac, const float* Bc, float cc) {
    float e = cc;
#pragma unroll
    for (int q = 0; q < 4; ++q) {
        e = fmaf(x[q].x, fmaf(Ac[q * 4 + 0], x[q].x, Bc[q * 4 + 0]), e);
        e = fmaf(x[q].y, fmaf(Ac[q * 4 + 1], x[q].y, Bc[q * 4 + 1]), e);
        e = fmaf(x[q].z, fmaf(Ac[q * 4 + 2], x[q].z, Bc[q * 4 + 2]), e);
        e = fmaf(x[q].w, fmaf(Ac[q * 4 + 3], x[q].w, Bc[q * 4 + 3]), e);
    }
    return e;
}

__device__ __forceinline__ float matvec64(float a, const float* p) {
    float acc0 = 0.f, acc1 = 0.f, acc2 = 0.f, acc3 = 0.f;
#pragma unroll
    for (int k = 0; k < KS; k += 4) {
        acc0 = fmaf(readlane_f(a, k + 0), p[k + 0], acc0);
        acc1 = fmaf(readlane_f(a, k + 1), p[k + 1], acc1);
        acc2 = fmaf(readlane_f(a, k + 2), p[k + 2], acc2);
        acc3 = fmaf(readlane_f(a, k + 3), p[k + 3], acc3);
    }
    return (acc0 + acc1) + (acc2 + acc3);
}

// One forward step. Entry: x = obs[tau]. Computes A_tau; stores ref row tau-1.
// LOAD: reload x with obs[tau+1] (in place, right after emis consumes x).
template<bool LOAD, bool STORE>
__device__ __forceinline__ void fwd_step(const float4*& xp, float4 x[4],
    const float* p, const float* Ac, const float* Bc, float cc,
    float& a, float& S, float& invrho, float& u_prev, float& invu_prev,
    float*& outp)
{
    float e = emis(x, Ac, Bc, cc);
    if (LOAD) {
        xp += 4;
        x[0] = xp[0]; x[1] = xp[1]; x[2] = xp[2]; x[3] = xp[3];
    }
    float w = __expf(e) * invu_prev;
    float an = matvec64(a, p) * w;             // A_tau
    float s_t = S * invrho;                    // stilde_{tau-1}
    float u = s_t + EPSV;
    float invu = rcp_f(u);
    if (STORE) { *outp = a * (invrho * invu); outp += KS; }   // ref row tau-1
    invrho = invrho * u_prev * invu;
    u_prev = u; invu_prev = invu;
    S = wave_sum(an);                          // off-chain; rejoins 2 steps later
    a = an;
}

// One backward step. Entry: x = obs[tau+1]. Computes B_tau; stores ref row tau+1.
// Always reloads x with obs[tau] (in-bounds for all tau >= 0).
template<bool STORE>
__device__ __forceinline__ void bwd_step(const float4*& xp, float4 x[4],
    const float* p, const float* Ac, const float* Bc, float cc,
    float& b, float& S, float& invrho, float& u_prev, float& invu_prev,
    float*& outp)
{
    float e = emis(x, Ac, Bc, cc);             // em[tau+1]
    xp -= 4;
    x[0] = xp[0]; x[1] = xp[1]; x[2] = xp[2]; x[3] = xp[3];
    float w = __expf(e) * invu_prev;
    float bn = matvec64(b * w, p);             // B_tau
    float s_t = S * invrho;                    // stilde_{tau+1}
    float u = s_t + EPSV;
    float invu = rcp_f(u);
    if (STORE) { *outp = b * (invrho * invu); outp -= KS; }   // ref row tau+1
    invrho = invrho * u_prev * invu;
    u_prev = u; invu_prev = invu;
    S = wave_sum(bn);
    b = bn;
}

extern "C" __global__ void __launch_bounds__(WPB * 64, 2)
hdphmm_fb(const float* __restrict__ obs, const float* __restrict__ beta_logits,
          const float* __restrict__ pi_logits, const float* __restrict__ means,
          const float* __restrict__ log_vars, float* __restrict__ out)
{
    const int lane = threadIdx.x & 63;
    const int g    = blockIdx.x * WPB + (threadIdx.x >> 6);   // global wave id
    const bool is_fwd = (g < C_CHUNKS);
    const int chunk   = is_fwd ? g : (g - C_CHUNKS);

    // ---- per-row softmax stats (row = lane), shared via readlane, no LDS ----
    float p[KS];
#pragma unroll
    for (int k = 0; k < KS; ++k) p[k] = pi_logits[lane * KS + k];
    float rm = -1e30f;
#pragma unroll
    for (int k = 0; k < KS; ++k) rm = fmaxf(rm, p[k]);
    float rs = 0.f;
#pragma unroll
    for (int k = 0; k < KS; ++k) rs += __expf(p[k] - rm);
    float ris = rcp_f(rs);

    if (is_fwd) {
        // fwd: lane j holds column j of P (coalesced column reload; setup-only)
#pragma unroll
        for (int k = 0; k < KS; ++k) {
            float mk = readlane_f(rm, k);
            float ik = readlane_f(ris, k);
            p[k] = __expf(pi_logits[k * KS + lane] - mk) * ik;
        }
    } else {
        // bwd: lane j holds row j of P (already in regs)
#pragma unroll
        for (int k = 0; k < KS; ++k)
            p[k] = __expf(p[k] - rm) * ris;
    }

    // ---- emission coefficients for state = lane ----
    float Ac[FD], Bc[FD];
    float cc = FD * LOG2PI;
#pragma unroll
    for (int f = 0; f < FD; ++f) {
        float lv = log_vars[lane * FD + f];
        float iv = __expf(-lv);
        float mu = means[lane * FD + f];
        Ac[f] = -0.5f * iv;
        Bc[f] = mu * iv;
        cc += lv + mu * mu * iv;
    }
    cc *= -0.5f;

    float* alpha = out;
    float* betap = out + (size_t)T_LEN * KS;

    // Deferred-normalization bookkeeping (exact eps semantics):
    //   propagated A_t = rho_t*atilde_t;  s_t = S_t*invrho_t;  u_t = s_t+EPS
    //   transition applies invu from two steps back; invrho_t = invrho_{t-1}*u_{t-2}*invu_{t-1}
    //   store: ref_row = A * invrho * invu   (one step late)

    if (is_fwd) {
        const int lo = chunk * L_CHUNK, hi = lo + L_CHUNK;
        float a, S;
        float invrho = 1.f, u_prev = 1.f, invu_prev = 1.f;
        float4 x[4];
        const float4* xp;
        float* outp;
        int nburn;
        if (chunk == 0) {
            // exact stick-breaking init at t = 0 : A_0 = atilde_0
            float bl = beta_logits[lane];
            float sg = rcp_f(1.f + __expf(-bl));
            float om = 1.f - sg;
            float prod = om;
#pragma unroll
            for (int d = 1; d < 64; d <<= 1) {
                float uu = __shfl_up(prod, d, 64);
                if (lane >= d) prod *= uu;
            }
            float ex = __shfl_up(prod, 1, 64);
            float w0 = sg * (lane == 0 ? 1.f : ex);
            xp = (const float4*)obs;               // row 0
            x[0] = xp[0]; x[1] = xp[1]; x[2] = xp[2]; x[3] = xp[3];
            float e = emis(x, Ac, Bc, cc);
            a = w0 * __expf(e);
            S = wave_sum(a);
            alpha[lane] = a * rcp_f(S + EPSV);     // row 0 (also rewritten by step 1)
            xp += 4;                                // row 1
            x[0] = xp[0]; x[1] = xp[1]; x[2] = xp[2]; x[3] = xp[3];
            nburn = 0;
            outp = alpha + lane;                    // step tau=1 stores row 0
        } else {
            a = 1.f / 64.f;   // arbitrary; burn-in forgets it
            S = 1.f;          // wave_sum of the uniform init, known exactly
            int tau0 = lo - BURN + 1;
            xp = (const float4*)(obs + (size_t)tau0 * FD);
            x[0] = xp[0]; x[1] = xp[1]; x[2] = xp[2]; x[3] = xp[3];
            nburn = BURN;     // taus tau0 .. lo
            outp = alpha + (size_t)lo * KS + lane;  // first store: row lo (at tau=lo+1)
        }
        for (int i = 0; i < nburn; ++i)
            fwd_step<true, false>(xp, x, p, Ac, Bc, cc, a, S, invrho, u_prev, invu_prev, outp);
        // main: 127 steps total; last one must not load past row hi-1
        for (int i = 0; i < L_CHUNK - 2; ++i)
            fwd_step<true, true>(xp, x, p, Ac, Bc, cc, a, S, invrho, u_prev, invu_prev, outp);
        fwd_step<false, true>(xp, x, p, Ac, Bc, cc, a, S, invrho, u_prev, invu_prev, outp);
        // epilogue: store row hi-1
        float s_t = S * invrho;
        float u = s_t + EPSV;
        float invu = rcp_f(u);
        *outp = a * (invrho * invu);
        if (hi == T_LEN) {
            float sa = s_t * invu;                 // sum(alpha[T-1])
            if (lane == 0) out[(size_t)2 * T_LEN * KS] = __logf(sa + EPSV);
        }
    } else {
        const int lo = chunk * L_CHUNK, hi = lo + L_CHUNK;
        float b, S;
        float invrho = 1.f, u_prev = 1.f, invu_prev = 1.f;
        float4 x[4];
        const float4* xp;
        float* outp;
        int nmain;
        if (hi == T_LEN) {
            betap[(size_t)(T_LEN - 1) * KS + lane] = 1.f;     // exact bT
            // peeled first step (tau = T-2): reference applies NO division to bT
            xp = (const float4*)(obs + (size_t)(T_LEN - 1) * FD);
            x[0] = xp[0]; x[1] = xp[1]; x[2] = xp[2]; x[3] = xp[3];
            float e = emis(x, Ac, Bc, cc);
            xp -= 4;                                // row T-2
            x[0] = xp[0]; x[1] = xp[1]; x[2] = xp[2]; x[3] = xp[3];
            float bn = matvec64(__expf(e), p);      // b = 1
            S = wave_sum(bn);
            b = bn;
            outp = betap + (size_t)(T_LEN - 2) * KS + lane;   // step T-3 stores row T-2
            nmain = L_CHUNK - 2;                    // taus T-3 .. lo
        } else {
            b = 1.f;      // arbitrary ones; burn-in forgets it
            S = 64.f;     // wave_sum of ones, known exactly
            int tstart = hi + BURN - 2;
            xp = (const float4*)(obs + (size_t)(tstart + 1) * FD);
            x[0] = xp[0]; x[1] = xp[1]; x[2] = xp[2]; x[3] = xp[3];
            // burn: taus tstart .. hi-1  (BURN steps), no stores
            for (int i = 0; i < BURN; ++i)
                bwd_step<false>(xp, x, p, Ac, Bc, cc, b, S, invrho, u_prev, invu_prev, outp);
            outp = betap + (size_t)(hi - 1) * KS + lane;      // step hi-2 stores row hi-1
            nmain = L_CHUNK - 1;                    // taus hi-2 .. lo
        }
        for (int i = 0; i < nmain; ++i)
            bwd_step<true>(xp, x, p, Ac, Bc, cc, b, S, invrho, u_prev, invu_prev, outp);
        // epilogue: store row lo
        float s_t = S * invrho;
        float u = s_t + EPSV;
        float invu = rcp_f(u);
        *outp = b * (invrho * invu);
    }
}

extern "C" void kernel_launch(void* const* d_in, const int* in_sizes, int n_in,
                              void* d_out, int out_size, void* d_ws, size_t ws_size,
                              hipStream_t stream) {
    const float* obs         = (const float*)d_in[0];
    const float* beta_logits = (const float*)d_in[1];
    const float* pi_logits   = (const float*)d_in[2];
    const float* means       = (const float*)d_in[3];
    const float* log_vars    = (const float*)d_in[4];
    float* out = (float*)d_out;
    (void)in_sizes; (void)n_in; (void)out_size; (void)d_ws; (void)ws_size;

    hipLaunchKernelGGL(hdphmm_fb, dim3(2 * C_CHUNKS / WPB), dim3(WPB * 64), 0, stream,
                       obs, beta_logits, pi_logits, means, log_vars, out);
}